// Round 1
// baseline (839.763 us; speedup 1.0000x reference)
//
#include <hip/hip_runtime.h>

// Problem constants (B=32, d=512, T=2048)
#define BB    32
#define DD    512
#define FOURD 2048
#define FIVED 2560
#define TT    2048
#define TV    (TT / 4)     // 512 float4 per row
#define PP    32           // number of partial rows (one per wave)

// Workspace requirement for the split-K path: PP * BB * 2 * TT * 4 bytes = 16 MiB
#define WS_BYTES ((size_t)PP * BB * 2 * TT * sizeof(float))

// ---------------------------------------------------------------------------
// NEW PATH — Kernel 1: wave-private partial logits (split-K over f).
// Grid (TT/256 = 8, BB = 32, 8 f-partitions), block = 256 threads = 4 waves.
// Wave w of partition z reduces G rows [z*256 + w*64, +64) and
// m rows [z*64 + w*16, +16) for a 256-wide t stripe (64 lanes x float4).
// Each wave writes its private partial: no cross-wave reduction, no barrier
// after the weight stage. 8192 waves total = full 32 waves/CU occupancy.
// ---------------------------------------------------------------------------
__global__ __launch_bounds__(256) void partial_kernel(
    const float* __restrict__ G,
    const float* __restrict__ m1,
    const float* __restrict__ m2,
    const float* __restrict__ wp1,
    const float* __restrict__ wp2,
    float* __restrict__ ws)
{
    __shared__ float s_w1g[256];
    __shared__ float s_w2g[256];
    __shared__ float s_w1m[64];
    __shared__ float s_w2m[64];

    const int tid  = threadIdx.x;
    const int b    = blockIdx.y;
    const int z    = blockIdx.z;

    // Stage this block's weight slice (2.5 KB).
    s_w1g[tid] = wp1[z * 256 + tid];
    s_w2g[tid] = wp2[z * 256 + tid];
    if (tid < 64) {
        s_w1m[tid] = wp1[FOURD + z * 64 + tid];
        s_w2m[tid] = wp2[FOURD + z * 64 + tid];
    }
    __syncthreads();

    const int lane = tid & 63;
    const int w    = tid >> 6;                    // wave id 0..3
    const int tv   = blockIdx.x * 64 + lane;      // float4 column 0..511

    const float4* Gv  = (const float4*)(G  + (size_t)b * FOURD * TT);
    const float4* m1v = (const float4*)(m1 + (size_t)b * DD    * TT);
    const float4* m2v = (const float4*)(m2 + (size_t)b * DD    * TT);

    float4 acc1 = make_float4(0.f, 0.f, 0.f, 0.f);
    float4 acc2 = make_float4(0.f, 0.f, 0.f, 0.f);

    // G part: 64 rows for this wave; each load is 1 KiB contiguous per wave.
    const int fg0 = z * 256 + w * 64;
    #pragma unroll 8
    for (int i = 0; i < 64; ++i) {
        const float4 g  = Gv[(size_t)(fg0 + i) * TV + tv];
        const float  w1 = s_w1g[w * 64 + i];
        const float  w2 = s_w2g[w * 64 + i];
        acc1.x += w1 * g.x; acc1.y += w1 * g.y; acc1.z += w1 * g.z; acc1.w += w1 * g.w;
        acc2.x += w2 * g.x; acc2.y += w2 * g.y; acc2.z += w2 * g.z; acc2.w += w2 * g.w;
    }

    // m part: 16 rows of m1 (p1) and m2 (p2) for this wave.
    const int fm0 = z * 64 + w * 16;
    #pragma unroll 8
    for (int i = 0; i < 16; ++i) {
        const float4 a  = m1v[(size_t)(fm0 + i) * TV + tv];
        const float4 c  = m2v[(size_t)(fm0 + i) * TV + tv];
        const float  w1 = s_w1m[w * 16 + i];
        const float  w2 = s_w2m[w * 16 + i];
        acc1.x += w1 * a.x; acc1.y += w1 * a.y; acc1.z += w1 * a.z; acc1.w += w1 * a.w;
        acc2.x += w2 * c.x; acc2.y += w2 * c.y; acc2.z += w2 * c.z; acc2.w += w2 * c.w;
    }

    // Write wave-private partials. Layout: ws[p][b][2][TV] as float4.
    const int p = z * 4 + w;
    float4* w4 = (float4*)ws;
    w4[((size_t)(p * BB + b) * 2 + 0) * TV + tv] = acc1;
    w4[((size_t)(p * BB + b) * 2 + 1) * TV + tv] = acc2;
}

// ---------------------------------------------------------------------------
// NEW PATH — Kernel 2: fused partial-reduce + row softmax.
// One block per (b, which) row: 64 blocks x 256 threads.
// Sums the 32 partials (16 MiB total, ~2.5 us), then softmax in registers.
// ---------------------------------------------------------------------------
__global__ __launch_bounds__(256) void reduce_softmax_kernel(
    const float* __restrict__ ws, float* __restrict__ out)
{
    const int row = blockIdx.x;        // b*2 + which, 0..63
    const int tid = threadIdx.x;
    const float4* w4 = (const float4*)ws;

    // Each thread owns float4 columns {tid, tid+256} of the 512-col row.
    float4 s0 = make_float4(0.f, 0.f, 0.f, 0.f);
    float4 s1 = make_float4(0.f, 0.f, 0.f, 0.f);
    #pragma unroll 8
    for (int p = 0; p < PP; ++p) {
        const float4* base = w4 + (size_t)(p * 64 + row) * TV;
        const float4 a = base[tid];
        const float4 c = base[tid + 256];
        s0.x += a.x; s0.y += a.y; s0.z += a.z; s0.w += a.w;
        s1.x += c.x; s1.y += c.y; s1.z += c.z; s1.w += c.w;
    }

    // Row max.
    float mx = fmaxf(fmaxf(fmaxf(s0.x, s0.y), fmaxf(s0.z, s0.w)),
                     fmaxf(fmaxf(s1.x, s1.y), fmaxf(s1.z, s1.w)));
    #pragma unroll
    for (int off = 32; off > 0; off >>= 1)
        mx = fmaxf(mx, __shfl_xor(mx, off, 64));

    __shared__ float sred[4];
    const int wave = tid >> 6;
    if ((tid & 63) == 0) sred[wave] = mx;
    __syncthreads();
    mx = fmaxf(fmaxf(sred[0], sred[1]), fmaxf(sred[2], sred[3]));
    __syncthreads();   // before sred reuse for the sum

    // Exp + row sum.
    float4 e0, e1;
    e0.x = __expf(s0.x - mx); e0.y = __expf(s0.y - mx);
    e0.z = __expf(s0.z - mx); e0.w = __expf(s0.w - mx);
    e1.x = __expf(s1.x - mx); e1.y = __expf(s1.y - mx);
    e1.z = __expf(s1.z - mx); e1.w = __expf(s1.w - mx);
    float sum = e0.x + e0.y + e0.z + e0.w + e1.x + e1.y + e1.z + e1.w;
    #pragma unroll
    for (int off = 32; off > 0; off >>= 1)
        sum += __shfl_xor(sum, off, 64);
    if ((tid & 63) == 0) sred[wave] = sum;
    __syncthreads();
    const float inv = 1.0f / (sred[0] + sred[1] + sred[2] + sred[3]);

    float4* o = (float4*)(out + (size_t)row * TT);
    e0.x *= inv; e0.y *= inv; e0.z *= inv; e0.w *= inv;
    e1.x *= inv; e1.y *= inv; e1.z *= inv; e1.w *= inv;
    o[tid]       = e0;
    o[tid + 256] = e1;
}

// ---------------------------------------------------------------------------
// FALLBACK PATH (previous verified kernels) — used only if ws_size < 16 MiB.
// ---------------------------------------------------------------------------
__global__ __launch_bounds__(256) void logits_kernel(
    const float* __restrict__ G,
    const float* __restrict__ m1,
    const float* __restrict__ m2,
    const float* __restrict__ wp1,
    const float* __restrict__ wp2,
    float* __restrict__ out)
{
    __shared__ float s_wp1[FIVED];
    __shared__ float s_wp2[FIVED];
    __shared__ float4 red1[8][32];
    __shared__ float4 red2[8][32];

    const int tid    = threadIdx.x;
    const int b      = blockIdx.y;
    const int t_base = blockIdx.x * 128;

    for (int i = tid; i < FIVED; i += 256) {
        s_wp1[i] = wp1[i];
        s_wp2[i] = wp2[i];
    }
    __syncthreads();

    const int t_group = tid & 31;
    const int f_part  = tid >> 5;
    const int tv      = (t_base >> 2) + t_group;

    const float4* Gv  = (const float4*)(G  + (size_t)b * FOURD * TT);
    const float4* m1v = (const float4*)(m1 + (size_t)b * DD    * TT);
    const float4* m2v = (const float4*)(m2 + (size_t)b * DD    * TT);

    float4 acc1 = make_float4(0.f, 0.f, 0.f, 0.f);
    float4 acc2 = make_float4(0.f, 0.f, 0.f, 0.f);

    const int fg0 = f_part * (FOURD / 8);
    #pragma unroll 4
    for (int i = 0; i < FOURD / 8; ++i) {
        const int f = fg0 + i;
        const float4 g = Gv[(size_t)f * TV + tv];
        const float w1 = s_wp1[f];
        const float w2 = s_wp2[f];
        acc1.x += w1 * g.x; acc1.y += w1 * g.y; acc1.z += w1 * g.z; acc1.w += w1 * g.w;
        acc2.x += w2 * g.x; acc2.y += w2 * g.y; acc2.z += w2 * g.z; acc2.w += w2 * g.w;
    }

    const int fm0 = f_part * (DD / 8);
    #pragma unroll 4
    for (int i = 0; i < DD / 8; ++i) {
        const int f = fm0 + i;
        const float4 a = m1v[(size_t)f * TV + tv];
        const float4 c = m2v[(size_t)f * TV + tv];
        const float w1 = s_wp1[FOURD + f];
        const float w2 = s_wp2[FOURD + f];
        acc1.x += w1 * a.x; acc1.y += w1 * a.y; acc1.z += w1 * a.z; acc1.w += w1 * a.w;
        acc2.x += w2 * c.x; acc2.y += w2 * c.y; acc2.z += w2 * c.z; acc2.w += w2 * c.w;
    }

    red1[f_part][t_group] = acc1;
    red2[f_part][t_group] = acc2;
    __syncthreads();

    if (tid < 64) {
        const int which = tid >> 5;
        const int tg    = tid & 31;
        float4 s = make_float4(0.f, 0.f, 0.f, 0.f);
        if (which == 0) {
            #pragma unroll
            for (int p = 0; p < 8; ++p) {
                const float4 v = red1[p][tg];
                s.x += v.x; s.y += v.y; s.z += v.z; s.w += v.w;
            }
        } else {
            #pragma unroll
            for (int p = 0; p < 8; ++p) {
                const float4 v = red2[p][tg];
                s.x += v.x; s.y += v.y; s.z += v.z; s.w += v.w;
            }
        }
        float4* o = (float4*)(out + (size_t)b * 2 * TT + (size_t)which * TT + t_base);
        o[tg] = s;
    }
}

__global__ __launch_bounds__(256) void softmax_kernel(float* __restrict__ out)
{
    const int row = blockIdx.x;
    float* p = out + (size_t)row * TT;
    const int tid = threadIdx.x;

    float v[8];
    float mx = -INFINITY;
    #pragma unroll
    for (int i = 0; i < 8; ++i) {
        v[i] = p[tid + i * 256];
        mx = fmaxf(mx, v[i]);
    }
    #pragma unroll
    for (int off = 32; off > 0; off >>= 1)
        mx = fmaxf(mx, __shfl_xor(mx, off, 64));

    __shared__ float sred[4];
    const int wave = tid >> 6;
    if ((tid & 63) == 0) sred[wave] = mx;
    __syncthreads();
    if (tid == 0) sred[0] = fmaxf(fmaxf(sred[0], sred[1]), fmaxf(sred[2], sred[3]));
    __syncthreads();
    mx = sred[0];
    __syncthreads();

    float sum = 0.f;
    #pragma unroll
    for (int i = 0; i < 8; ++i) {
        v[i] = __expf(v[i] - mx);
        sum += v[i];
    }
    #pragma unroll
    for (int off = 32; off > 0; off >>= 1)
        sum += __shfl_xor(sum, off, 64);
    if ((tid & 63) == 0) sred[wave] = sum;
    __syncthreads();
    if (tid == 0) sred[0] = sred[0] + sred[1] + sred[2] + sred[3];
    __syncthreads();
    const float inv = 1.0f / sred[0];

    #pragma unroll
    for (int i = 0; i < 8; ++i)
        p[tid + i * 256] = v[i] * inv;
}

extern "C" void kernel_launch(void* const* d_in, const int* in_sizes, int n_in,
                              void* d_out, int out_size, void* d_ws, size_t ws_size,
                              hipStream_t stream) {
    const float* G   = (const float*)d_in[0];
    const float* m1  = (const float*)d_in[1];
    const float* m2  = (const float*)d_in[2];
    const float* wp1 = (const float*)d_in[3];
    const float* wp2 = (const float*)d_in[4];
    float* out = (float*)d_out;

    if (d_ws != nullptr && ws_size >= WS_BYTES) {
        // Split-K path: full occupancy, wave-private partials.
        float* ws = (float*)d_ws;
        dim3 grid1(TT / 256, BB, 8);
        partial_kernel<<<grid1, 256, 0, stream>>>(G, m1, m2, wp1, wp2, ws);
        reduce_softmax_kernel<<<BB * 2, 256, 0, stream>>>(ws, out);
    } else {
        // Fallback: previous verified kernels.
        dim3 grid1(TT / 128, BB);
        logits_kernel<<<grid1, 256, 0, stream>>>(G, m1, m2, wp1, wp2, out);
        softmax_kernel<<<BB * 2, 256, 0, stream>>>(out);
    }
}

// Round 2
// 813.213 us; speedup vs baseline: 1.0326x; 1.0326x over previous
//
#include <hip/hip_runtime.h>

// Problem constants (B=32, d=512, T=2048)
#define BB    32
#define DD    512
#define FOURD 2048
#define FIVED 2560
#define TT    2048
#define TV    (TT / 4)     // 512 float4 per row

// ---------------------------------------------------------------------------
// Kernel 1: fused dual logit reduction (single pass, no workspace).
// p1[b,t] = sum_f wp1[f]*G[b,f,t] (f<4d) + sum_f wp1[4d+f]*m1[b,f,t]
// p2[b,t] = sum_f wp2[f]*G[b,f,t] (f<4d) + sum_f wp2[4d+f]*m2[b,f,t]
// G is read ONCE and feeds both accumulators (halves HBM traffic vs naive).
// Block: 256 threads = 32 t-groups (x4 t via float4) x 8 f-parts.
// Grid: (T/128, B) = 512 blocks, 8 waves/CU.
//
// NOTE (session finding, round 1): the bench's timed window includes two
// ~2.1 GiB workspace-poison fills (~684 us total) that are unconditional —
// they run whether or not d_ws is touched. Kernel-side traffic floor is
// 805 MB / 6.3 TB/s ~= 128 us, which this structure already achieves.
// The split-K/workspace variant (round 1) only added ~27 us of partial
// write/read + launch overhead. Do not reintroduce workspace use.
// ---------------------------------------------------------------------------
__global__ __launch_bounds__(256) void logits_kernel(
    const float* __restrict__ G,
    const float* __restrict__ m1,
    const float* __restrict__ m2,
    const float* __restrict__ wp1,
    const float* __restrict__ wp2,
    float* __restrict__ out)
{
    __shared__ float s_wp1[FIVED];
    __shared__ float s_wp2[FIVED];
    __shared__ float4 red1[8][32];
    __shared__ float4 red2[8][32];

    const int tid    = threadIdx.x;
    const int b      = blockIdx.y;
    const int t_base = blockIdx.x * 128;

    // Stage weight vectors into LDS (10 KB each).
    for (int i = tid; i < FIVED; i += 256) {
        s_wp1[i] = wp1[i];
        s_wp2[i] = wp2[i];
    }
    __syncthreads();

    const int t_group = tid & 31;   // which 4-wide t chunk
    const int f_part  = tid >> 5;   // which slice of the f reduction
    const int tv      = (t_base >> 2) + t_group;

    const float4* Gv  = (const float4*)(G  + (size_t)b * FOURD * TT);
    const float4* m1v = (const float4*)(m1 + (size_t)b * DD    * TT);
    const float4* m2v = (const float4*)(m2 + (size_t)b * DD    * TT);

    float4 acc1 = make_float4(0.f, 0.f, 0.f, 0.f);
    float4 acc2 = make_float4(0.f, 0.f, 0.f, 0.f);

    // G part: this f_part covers 2048/8 = 256 rows.
    const int fg0 = f_part * (FOURD / 8);
    #pragma unroll 4
    for (int i = 0; i < FOURD / 8; ++i) {
        const int f = fg0 + i;
        const float4 g = Gv[(size_t)f * TV + tv];
        const float w1 = s_wp1[f];
        const float w2 = s_wp2[f];
        acc1.x += w1 * g.x; acc1.y += w1 * g.y; acc1.z += w1 * g.z; acc1.w += w1 * g.w;
        acc2.x += w2 * g.x; acc2.y += w2 * g.y; acc2.z += w2 * g.z; acc2.w += w2 * g.w;
    }

    // m part: this f_part covers 512/8 = 64 rows of m1 (for p1) and m2 (for p2).
    const int fm0 = f_part * (DD / 8);
    #pragma unroll 4
    for (int i = 0; i < DD / 8; ++i) {
        const int f = fm0 + i;
        const float4 a = m1v[(size_t)f * TV + tv];
        const float4 c = m2v[(size_t)f * TV + tv];
        const float w1 = s_wp1[FOURD + f];
        const float w2 = s_wp2[FOURD + f];
        acc1.x += w1 * a.x; acc1.y += w1 * a.y; acc1.z += w1 * a.z; acc1.w += w1 * a.w;
        acc2.x += w2 * c.x; acc2.y += w2 * c.y; acc2.z += w2 * c.z; acc2.w += w2 * c.w;
    }

    red1[f_part][t_group] = acc1;
    red2[f_part][t_group] = acc2;
    __syncthreads();

    // Reduce 8 f-parts. Threads 0..31 handle p1, 32..63 handle p2.
    if (tid < 64) {
        const int which = tid >> 5;   // 0 -> p1, 1 -> p2
        const int tg    = tid & 31;
        float4 s = make_float4(0.f, 0.f, 0.f, 0.f);
        if (which == 0) {
            #pragma unroll
            for (int p = 0; p < 8; ++p) {
                const float4 v = red1[p][tg];
                s.x += v.x; s.y += v.y; s.z += v.z; s.w += v.w;
            }
        } else {
            #pragma unroll
            for (int p = 0; p < 8; ++p) {
                const float4 v = red2[p][tg];
                s.x += v.x; s.y += v.y; s.z += v.z; s.w += v.w;
            }
        }
        float4* o = (float4*)(out + (size_t)b * 2 * TT + (size_t)which * TT + t_base);
        o[tg] = s;
    }
}

// ---------------------------------------------------------------------------
// Kernel 2: in-place row softmax. One block per (b, which) row: 64 blocks.
// 256 threads, 8 elements/thread.
// ---------------------------------------------------------------------------
__global__ __launch_bounds__(256) void softmax_kernel(float* __restrict__ out)
{
    const int row = blockIdx.x;            // 0..63
    float* p = out + (size_t)row * TT;
    const int tid = threadIdx.x;

    float v[8];
    float mx = -INFINITY;
    #pragma unroll
    for (int i = 0; i < 8; ++i) {
        v[i] = p[tid + i * 256];
        mx = fmaxf(mx, v[i]);
    }

    // Wave (64-lane) max reduction.
    #pragma unroll
    for (int off = 32; off > 0; off >>= 1)
        mx = fmaxf(mx, __shfl_xor(mx, off, 64));

    __shared__ float sred[4];
    const int wave = tid >> 6;
    if ((tid & 63) == 0) sred[wave] = mx;
    __syncthreads();
    if (tid == 0) {
        sred[0] = fmaxf(fmaxf(sred[0], sred[1]), fmaxf(sred[2], sred[3]));
    }
    __syncthreads();
    mx = sred[0];
    __syncthreads();   // before sred reuse for sum

    float sum = 0.f;
    #pragma unroll
    for (int i = 0; i < 8; ++i) {
        v[i] = __expf(v[i] - mx);
        sum += v[i];
    }
    #pragma unroll
    for (int off = 32; off > 0; off >>= 1)
        sum += __shfl_xor(sum, off, 64);
    if ((tid & 63) == 0) sred[wave] = sum;
    __syncthreads();
    if (tid == 0) {
        sred[0] = sred[0] + sred[1] + sred[2] + sred[3];
    }
    __syncthreads();
    const float inv = 1.0f / sred[0];

    #pragma unroll
    for (int i = 0; i < 8; ++i)
        p[tid + i * 256] = v[i] * inv;
}

extern "C" void kernel_launch(void* const* d_in, const int* in_sizes, int n_in,
                              void* d_out, int out_size, void* d_ws, size_t ws_size,
                              hipStream_t stream) {
    const float* G   = (const float*)d_in[0];
    const float* m1  = (const float*)d_in[1];
    const float* m2  = (const float*)d_in[2];
    const float* wp1 = (const float*)d_in[3];
    const float* wp2 = (const float*)d_in[4];
    float* out = (float*)d_out;

    dim3 grid1(TT / 128, BB);
    logits_kernel<<<grid1, 256, 0, stream>>>(G, m1, m2, wp1, wp2, out);
    softmax_kernel<<<BB * 2, 256, 0, stream>>>(out);
}